// Round 8
// baseline (1035.995 us; speedup 1.0000x reference)
//
#include <hip/hip_runtime.h>
#include <hip/hip_bf16.h>

#define NN 100000
#define NE 1600000
#define HID 512
#define LOW 128
#define NR  6
#define NBINS (NN * NR)

typedef short  bf16x8 __attribute__((ext_vector_type(8)));
typedef float  f32x4  __attribute__((ext_vector_type(4)));

__device__ __forceinline__ unsigned short f2bf(float x) {
    __hip_bfloat16 h = __float2bfloat16(x);
    return __builtin_bit_cast(unsigned short, h);
}
__device__ __forceinline__ float bf2f(unsigned short u) {
    return __builtin_bit_cast(float, (unsigned int)u << 16);
}

// ---------------------------------------------------------------------------
// Tile staging (256 threads): global bf16 [rows][Kstride] -> LDS [128][64]
// bf16 (16 KB); 16B chunks XOR-swizzled by (row&7) via pre-swizzled SOURCE.
// ---------------------------------------------------------------------------
__device__ __forceinline__ void stage_tile(const unsigned short* __restrict__ G,
                                           int r0, int k0, int Kstride, int Rmax,
                                           char* lds_base, int tid)
{
    #pragma unroll
    for (int is = 0; is < 4; ++is) {
        int L   = is * 4096 + tid * 16;
        int row = L >> 7;
        int c   = ((L >> 4) & 7) ^ (row & 7);
        int gr  = r0 + row;
        gr = (gr < Rmax) ? gr : (Rmax - 1);
        const char* src = (const char*)G + ((size_t)gr * Kstride + k0) * 2 + c * 16;
        __builtin_amdgcn_global_load_lds(
            (const __attribute__((address_space(1))) void*)src,
            (__attribute__((address_space(3))) void*)(lds_base + is * 4096 + (tid & 192) * 16),
            16, 0, 0);
    }
}

// 512-thread variants for the BM=256 fused-output kernel.
__device__ __forceinline__ void stage_tile256(const unsigned short* __restrict__ G,
                                              int r0, int k0, int Kstride, int Rmax,
                                              char* lds_base, int tid)
{
    #pragma unroll
    for (int is = 0; is < 4; ++is) {          // 4 x 8 KB = 32 KB (256 rows)
        int L   = is * 8192 + tid * 16;
        int row = L >> 7;
        int c   = ((L >> 4) & 7) ^ (row & 7);
        int gr  = r0 + row;
        gr = (gr < Rmax) ? gr : (Rmax - 1);
        const char* src = (const char*)G + ((size_t)gr * Kstride + k0) * 2 + c * 16;
        __builtin_amdgcn_global_load_lds(
            (const __attribute__((address_space(1))) void*)src,
            (__attribute__((address_space(3))) void*)(lds_base + is * 8192 + (tid >> 6) * 1024),
            16, 0, 0);
    }
}

__device__ __forceinline__ void stage_tile128_512(const unsigned short* __restrict__ G,
                                                  int r0, int k0, int Kstride, int Rmax,
                                                  char* lds_base, int tid)
{
    #pragma unroll
    for (int is = 0; is < 2; ++is) {          // 2 x 8 KB = 16 KB (128 rows)
        int L   = is * 8192 + tid * 16;
        int row = L >> 7;
        int c   = ((L >> 4) & 7) ^ (row & 7);
        int gr  = r0 + row;
        gr = (gr < Rmax) ? gr : (Rmax - 1);
        const char* src = (const char*)G + ((size_t)gr * Kstride + k0) * 2 + c * 16;
        __builtin_amdgcn_global_load_lds(
            (const __attribute__((address_space(1))) void*)src,
            (__attribute__((address_space(3))) void*)(lds_base + is * 8192 + (tid >> 6) * 1024),
            16, 0, 0);
    }
}

__device__ __forceinline__ bf16x8 lds_frag(const char* lds_base, int row, int clog)
{
    return *(const bf16x8*)(lds_base + row * 128 + ((clog ^ (row & 7)) << 4));
}

// ---------------------------------------------------------------------------
// bf16 MFMA GEMM: C(bf16) = [relu(A @ Bt^T + bias)] or raw A @ Bt^T.
// 128x128 tile, 4 waves.
// ---------------------------------------------------------------------------
template<bool RELU>
__global__ __launch_bounds__(256, 2)
void gemm_bf16(const unsigned short* __restrict__ A,
               const unsigned short* __restrict__ Bt,
               const float* __restrict__ bias,
               unsigned short* __restrict__ C,
               int M, int N, int K)
{
    __shared__ __align__(16) char lA[16384];
    __shared__ __align__(16) char lB[16384];

    const int tid  = threadIdx.x;
    const int lane = tid & 63;
    const int wid  = tid >> 6;
    const int wm   = wid >> 1;
    const int wn   = wid & 1;
    const int m0   = blockIdx.y * 128;
    const int n0   = blockIdx.x * 128;

    f32x4 acc[4][4] = {};

    for (int k0 = 0; k0 < K; k0 += 64) {
        stage_tile(A,  m0, k0, K, M, lA, tid);
        stage_tile(Bt, n0, k0, K, N, lB, tid);
        __syncthreads();
        #pragma unroll
        for (int kk = 0; kk < 2; ++kk) {
            const int clog = kk * 4 + (lane >> 4);
            bf16x8 af[4], bfr[4];
            #pragma unroll
            for (int i = 0; i < 4; ++i)
                af[i] = lds_frag(lA, wm * 64 + i * 16 + (lane & 15), clog);
            #pragma unroll
            for (int j = 0; j < 4; ++j)
                bfr[j] = lds_frag(lB, wn * 64 + j * 16 + (lane & 15), clog);
            #pragma unroll
            for (int i = 0; i < 4; ++i)
                #pragma unroll
                for (int j = 0; j < 4; ++j)
                    acc[i][j] = __builtin_amdgcn_mfma_f32_16x16x32_bf16(
                        af[i], bfr[j], acc[i][j], 0, 0, 0);
        }
        __syncthreads();
    }

    const int col_l = lane & 15;
    const int rgrp  = lane >> 4;
    #pragma unroll
    for (int i = 0; i < 4; ++i) {
        #pragma unroll
        for (int j = 0; j < 4; ++j) {
            int col  = n0 + wn * 64 + j * 16 + col_l;
            float bv = RELU ? bias[col] : 0.f;
            #pragma unroll
            for (int r = 0; r < 4; ++r) {
                int row = m0 + wm * 64 + i * 16 + rgrp * 4 + r;
                if (row < M) {
                    float v = acc[i][j][r];
                    if constexpr (RELU) v = fmaxf(v + bv, 0.f);
                    C[(size_t)row * N + col] = f2bf(v);
                }
            }
        }
    }
}

// ---------------------------------------------------------------------------
// Fused output (BM=256, 512 threads, 8 waves):
// out(f32) = relu(h @ Wut^T + bu) + relu(hob @ Wst^T + bs)
// Bijective XCD swizzle (nwg=1564): 4 n-tiles of each 256-row slab share XCD.
// ---------------------------------------------------------------------------
__global__ __launch_bounds__(512, 4)
void gemm_out_fused(const unsigned short* __restrict__ h,
                    const unsigned short* __restrict__ Wut,
                    const float* __restrict__ bu,
                    const unsigned short* __restrict__ hob,
                    const unsigned short* __restrict__ Wst,
                    const float* __restrict__ bs,
                    float* __restrict__ out, int M)
{
    __shared__ __align__(16) char lA[32768];
    __shared__ __align__(16) char lB[16384];

    const int tid  = threadIdx.x;
    const int lane = tid & 63;
    const int wid  = tid >> 6;     // 0..7
    const int wm   = wid >> 1;     // 0..3 (m sub-slab of 64)
    const int wn   = wid & 1;      // 0..1 (n sub-slab of 64)

    const int nwg = gridDim.x;
    const int q = nwg >> 3, r = nwg & 7;
    const int xcd = blockIdx.x & 7;
    const int base = (xcd < r) ? xcd * (q + 1) : r * (q + 1) + (xcd - r) * q;
    const int idx  = base + (blockIdx.x >> 3);
    const int m0   = (idx >> 2) * 256;
    const int n0   = (idx & 3) * 128;

    f32x4 acc1[4][4] = {};
    f32x4 acc2[4][4] = {};

    for (int k0 = 0; k0 < LOW; k0 += 64) {
        stage_tile256(h, m0, k0, LOW, M, lA, tid);
        stage_tile128_512(Wut, n0, k0, LOW, HID, lB, tid);
        __syncthreads();
        #pragma unroll
        for (int kk = 0; kk < 2; ++kk) {
            const int clog = kk * 4 + (lane >> 4);
            bf16x8 af[4], bfr[4];
            #pragma unroll
            for (int i = 0; i < 4; ++i)
                af[i] = lds_frag(lA, wm * 64 + i * 16 + (lane & 15), clog);
            #pragma unroll
            for (int j = 0; j < 4; ++j)
                bfr[j] = lds_frag(lB, wn * 64 + j * 16 + (lane & 15), clog);
            #pragma unroll
            for (int i = 0; i < 4; ++i)
                #pragma unroll
                for (int j = 0; j < 4; ++j)
                    acc1[i][j] = __builtin_amdgcn_mfma_f32_16x16x32_bf16(
                        af[i], bfr[j], acc1[i][j], 0, 0, 0);
        }
        __syncthreads();
    }
    for (int k0 = 0; k0 < HID; k0 += 64) {
        stage_tile256(hob, m0, k0, HID, M, lA, tid);
        stage_tile128_512(Wst, n0, k0, HID, HID, lB, tid);
        __syncthreads();
        #pragma unroll
        for (int kk = 0; kk < 2; ++kk) {
            const int clog = kk * 4 + (lane >> 4);
            bf16x8 af[4], bfr[4];
            #pragma unroll
            for (int i = 0; i < 4; ++i)
                af[i] = lds_frag(lA, wm * 64 + i * 16 + (lane & 15), clog);
            #pragma unroll
            for (int j = 0; j < 4; ++j)
                bfr[j] = lds_frag(lB, wn * 64 + j * 16 + (lane & 15), clog);
            #pragma unroll
            for (int i = 0; i < 4; ++i)
                #pragma unroll
                for (int j = 0; j < 4; ++j)
                    acc2[i][j] = __builtin_amdgcn_mfma_f32_16x16x32_bf16(
                        af[i], bfr[j], acc2[i][j], 0, 0, 0);
        }
        __syncthreads();
    }

    const int col_l = lane & 15;
    const int rgrp  = lane >> 4;
    #pragma unroll
    for (int i = 0; i < 4; ++i) {
        #pragma unroll
        for (int j = 0; j < 4; ++j) {
            int col   = n0 + wn * 64 + j * 16 + col_l;
            float bv1 = bu[col], bv2 = bs[col];
            #pragma unroll
            for (int rr = 0; rr < 4; ++rr) {
                int row = m0 + wm * 64 + i * 16 + rgrp * 4 + rr;
                if (row < M)
                    out[(size_t)row * HID + col] =
                        fmaxf(acc1[i][j][rr] + bv1, 0.f) + fmaxf(acc2[i][j][rr] + bv2, 0.f);
            }
        }
    }
}

// ---------------------------------------------------------------------------
// Conversions
// ---------------------------------------------------------------------------
__global__ __launch_bounds__(256)
void conv_f32_bf16(const float4* __restrict__ in, ushort4* __restrict__ out, int n4)
{
    for (int i = blockIdx.x * 256 + threadIdx.x; i < n4; i += gridDim.x * 256) {
        float4 v = in[i];
        ushort4 o;
        o.x = f2bf(v.x); o.y = f2bf(v.y); o.z = f2bf(v.z); o.w = f2bf(v.w);
        out[i] = o;
    }
}

// Wt[c][r] = bf16(W[r][c]);  W is [R,C] f32.
__global__ __launch_bounds__(256)
void transpose_bf16(const float* __restrict__ W, unsigned short* __restrict__ Wt,
                    int R, int C)
{
    int idx = blockIdx.x * 256 + threadIdx.x;
    if (idx < R * C) {
        int r = idx / C, c = idx - r * C;
        Wt[(size_t)c * R + r] = f2bf(W[idx]);
    }
}

// R-GCN weight for transform-first: Wt[(r*128+e)*128 + d] = W[(r*128+d)*128 + e]
__global__ __launch_bounds__(256)
void transpose_rgcn(const float* __restrict__ W, unsigned short* __restrict__ Wt)
{
    int idx = blockIdx.x * 256 + threadIdx.x;
    if (idx < NR * LOW * LOW) {
        int r   = idx >> 14;
        int rem = idx & 16383;
        int d   = rem >> 7;
        int e   = rem & 127;
        Wt[(size_t)(r * LOW + e) * LOW + d] = f2bf(W[idx]);
    }
}

// ---------------------------------------------------------------------------
// CSR build keyed by bin = dst*NR + rel. Parallel 3-kernel exclusive scan.
// list entry stores src*NR + rel  (row index into t [NN*NR][128]).
// ---------------------------------------------------------------------------
#define SCAN_VT 8
#define SCAN_BS 256
#define SCAN_CHUNK (SCAN_VT * SCAN_BS)
#define SCAN_NB ((NBINS + SCAN_CHUNK - 1) / SCAN_CHUNK)

__global__ __launch_bounds__(256)
void k_hist(const int* __restrict__ dst, const int* __restrict__ typ,
            int* __restrict__ deg, int E)
{
    int e = blockIdx.x * 256 + threadIdx.x;
    if (e < E) atomicAdd(&deg[dst[e] * NR + typ[e]], 1);
}

__global__ __launch_bounds__(SCAN_BS)
void k_scan_part(const int* __restrict__ deg, int* __restrict__ blocksum, int n)
{
    __shared__ int ps[SCAN_BS];
    const int t = threadIdx.x;
    const int lo = blockIdx.x * SCAN_CHUNK + t * SCAN_VT;
    int s = 0;
    #pragma unroll
    for (int k = 0; k < SCAN_VT; ++k) {
        int i = lo + k;
        if (i < n) s += deg[i];
    }
    ps[t] = s;
    __syncthreads();
    for (int off = SCAN_BS / 2; off > 0; off >>= 1) {
        if (t < off) ps[t] += ps[t + off];
        __syncthreads();
    }
    if (t == 0) blocksum[blockIdx.x] = ps[0];
}

__global__ __launch_bounds__(64)
void k_scan_mid(const int* __restrict__ blocksum, int* __restrict__ blockoff,
                int* __restrict__ rowstart, int nb, int n)
{
    if (threadIdx.x == 0) {
        int run = 0;
        for (int i = 0; i < nb; ++i) { blockoff[i] = run; run += blocksum[i]; }
        rowstart[n] = run;
    }
}

__global__ __launch_bounds__(SCAN_BS)
void k_scan_final(const int* __restrict__ deg, const int* __restrict__ blockoff,
                  int* __restrict__ rowstart, int* __restrict__ cursor, int n)
{
    __shared__ int ps[SCAN_BS];
    const int t = threadIdx.x;
    const int lo = blockIdx.x * SCAN_CHUNK + t * SCAN_VT;
    int local[SCAN_VT];
    int s = 0;
    #pragma unroll
    for (int k = 0; k < SCAN_VT; ++k) {
        int i = lo + k;
        int v = (i < n) ? deg[i] : 0;
        local[k] = v;
        s += v;
    }
    ps[t] = s;
    __syncthreads();
    for (int off = 1; off < SCAN_BS; off <<= 1) {
        int v = (t >= off) ? ps[t - off] : 0;
        __syncthreads();
        ps[t] += v;
        __syncthreads();
    }
    int run = blockoff[blockIdx.x] + ((t > 0) ? ps[t - 1] : 0);
    #pragma unroll
    for (int k = 0; k < SCAN_VT; ++k) {
        int i = lo + k;
        if (i < n) {
            rowstart[i] = run;
            cursor[i]   = run;
            run += local[k];
        }
    }
}

__global__ __launch_bounds__(256)
void k_fill(const int* __restrict__ src, const int* __restrict__ dst,
            const int* __restrict__ typ, int* __restrict__ cursor,
            int* __restrict__ list, int E)
{
    int e = blockIdx.x * 256 + threadIdx.x;
    if (e < E) {
        int ty = typ[e];
        int pos = atomicAdd(&cursor[dst[e] * NR + ty], 1);
        list[pos] = src[e] * NR + ty;
    }
}

// ---------------------------------------------------------------------------
// Gather-aggregate over transformed rows t: HALF-WAVE per dst node; lane owns
// channels 4c..4c+3 (ushort4). ONE merged edge range per node, 8-deep chains.
// Epilogue: h'[v] = relu(sum + bias).
// ---------------------------------------------------------------------------
__global__ __launch_bounds__(256)
void gather_agg(const unsigned short* __restrict__ t,
                const int* __restrict__ rowstart,
                const int* __restrict__ list,
                const float* __restrict__ bias,
                unsigned short* __restrict__ hn)
{
    const int v = (blockIdx.x * 256 + threadIdx.x) >> 5;
    if (v >= NN) return;
    const int lane = threadIdx.x & 31;
    const ushort4* tp = (const ushort4*)t;

    const int b0 = rowstart[v * NR];
    const int b6 = rowstart[v * NR + NR];

    float acc[8][4] = {};

    for (int k = b0; k < b6; k += 8) {
        #pragma unroll
        for (int c = 0; c < 8; ++c) {
            int idx   = k + c;
            bool ok   = (idx < b6);
            int li    = ok ? idx : 0;
            int rowid = list[li];
            ushort4 u = tp[(size_t)rowid * 32 + lane];
            acc[c][0] += ok ? bf2f(u.x) : 0.f;
            acc[c][1] += ok ? bf2f(u.y) : 0.f;
            acc[c][2] += ok ? bf2f(u.z) : 0.f;
            acc[c][3] += ok ? bf2f(u.w) : 0.f;
        }
    }

    float4 bv = *(const float4*)(bias + lane * 4);
    float s0 = ((acc[0][0] + acc[1][0]) + (acc[2][0] + acc[3][0])) +
               ((acc[4][0] + acc[5][0]) + (acc[6][0] + acc[7][0])) + bv.x;
    float s1 = ((acc[0][1] + acc[1][1]) + (acc[2][1] + acc[3][1])) +
               ((acc[4][1] + acc[5][1]) + (acc[6][1] + acc[7][1])) + bv.y;
    float s2 = ((acc[0][2] + acc[1][2]) + (acc[2][2] + acc[3][2])) +
               ((acc[4][2] + acc[5][2]) + (acc[6][2] + acc[7][2])) + bv.z;
    float s3 = ((acc[0][3] + acc[1][3]) + (acc[2][3] + acc[3][3])) +
               ((acc[4][3] + acc[5][3]) + (acc[6][3] + acc[7][3])) + bv.w;

    ushort4 w;
    w.x = f2bf(fmaxf(s0, 0.f));
    w.y = f2bf(fmaxf(s1, 0.f));
    w.z = f2bf(fmaxf(s2, 0.f));
    w.w = f2bf(fmaxf(s3, 0.f));
    ((ushort4*)(hn + (size_t)v * LOW))[lane] = w;
}

extern "C" void kernel_launch(void* const* d_in, const int* in_sizes, int n_in,
                              void* d_out, int out_size, void* d_ws, size_t ws_size,
                              hipStream_t stream)
{
    (void)in_sizes; (void)n_in; (void)out_size; (void)ws_size;

    const float* h_origin = (const float*)d_in[0];
    const int*   esrc     = (const int*)d_in[1];
    const int*   edst     = (const int*)d_in[2];
    const int*   etyp     = (const int*)d_in[3];
    const float* W_lower  = (const float*)d_in[4];
    const float* b_lower  = (const float*)d_in[5];
    const float* Wl[3]    = {(const float*)d_in[6], (const float*)d_in[8], (const float*)d_in[10]};
    const float* bl[3]    = {(const float*)d_in[7], (const float*)d_in[9], (const float*)d_in[11]};
    const float* W_upper  = (const float*)d_in[12];
    const float* b_upper  = (const float*)d_in[13];
    const float* W_skip   = (const float*)d_in[14];
    const float* b_skip   = (const float*)d_in[15];
    float*       out      = (float*)d_out;

    // Workspace layout
    unsigned short* hob = (unsigned short*)d_ws;          // [NN,512] bf16
    unsigned short* h   = hob + (size_t)NN * HID;         // [NN,128]
    unsigned short* t   = h + (size_t)NN * LOW;           // [NN,768] transformed
    unsigned short* wlt = t + (size_t)NN * NR * LOW;      // [128,512]
    unsigned short* w1t = wlt + (size_t)LOW * HID;        // [768,128] x3
    unsigned short* w2t = w1t + (size_t)NR * LOW * LOW;
    unsigned short* w3t = w2t + (size_t)NR * LOW * LOW;
    unsigned short* wut = w3t + (size_t)NR * LOW * LOW;   // [512,128]
    unsigned short* wst = wut + (size_t)HID * LOW;        // [512,512]
    int* deg      = (int*)(wst + (size_t)HID * HID);      // [NBINS]
    int* rowstart = deg + NBINS;                          // [NBINS+1]
    int* cursor   = rowstart + NBINS + 1;                 // [NBINS]
    int* list     = cursor + NBINS;                       // [NE]
    int* blocksum = list + NE;                            // [SCAN_NB]
    int* blockoff = blocksum + SCAN_NB;                   // [SCAN_NB]
    unsigned short* wtL[3] = {w1t, w2t, w3t};

    const unsigned eBlocks = (unsigned)((NE + 255) / 256);
    const unsigned mBlocks = (unsigned)((NN + 127) / 128);   // 782

    // ---- conversions ----
    conv_f32_bf16<<<dim3(2048), dim3(256), 0, stream>>>(
        (const float4*)h_origin, (ushort4*)hob, NN * HID / 4);
    transpose_bf16<<<dim3((HID * LOW + 255) / 256), dim3(256), 0, stream>>>(
        W_lower, wlt, HID, LOW);
    for (int L = 0; L < 3; ++L)
        transpose_rgcn<<<dim3((NR * LOW * LOW + 255) / 256), dim3(256), 0, stream>>>(
            Wl[L], wtL[L]);
    transpose_bf16<<<dim3((LOW * HID + 255) / 256), dim3(256), 0, stream>>>(
        W_upper, wut, LOW, HID);
    transpose_bf16<<<dim3((HID * HID + 255) / 256), dim3(256), 0, stream>>>(
        W_skip, wst, HID, HID);

    // ---- CSR build over (dst, rel) bins ----
    hipMemsetAsync(deg, 0, NBINS * sizeof(int), stream);
    k_hist<<<dim3(eBlocks), dim3(256), 0, stream>>>(edst, etyp, deg, NE);
    k_scan_part<<<dim3(SCAN_NB), dim3(SCAN_BS), 0, stream>>>(deg, blocksum, NBINS);
    k_scan_mid<<<dim3(1), dim3(64), 0, stream>>>(blocksum, blockoff, rowstart, SCAN_NB, NBINS);
    k_scan_final<<<dim3(SCAN_NB), dim3(SCAN_BS), 0, stream>>>(deg, blockoff, rowstart, cursor, NBINS);
    k_fill<<<dim3(eBlocks), dim3(256), 0, stream>>>(esrc, edst, etyp, cursor, list, NE);

    // ---- lower: h = relu(hob @ wlt^T + b_lower) ----
    gemm_bf16<true><<<dim3(1, mBlocks), dim3(256), 0, stream>>>(
        hob, wlt, b_lower, h, NN, LOW, HID);

    // ---- 3 R-GCN layers: transform-first (t = h @ Wcat^T), then gather ----
    const unsigned gBlocks = (unsigned)(((size_t)NN * 32 + 255) / 256);
    for (int L = 0; L < 3; ++L) {
        gemm_bf16<false><<<dim3(NR, mBlocks), dim3(256), 0, stream>>>(
            h, wtL[L], nullptr, t, NN, NR * LOW, LOW);
        gather_agg<<<dim3(gBlocks), dim3(256), 0, stream>>>(
            t, rowstart, list, bl[L], h);
    }

    // ---- fused output (BM=256, 512 threads, bijective XCD swizzle) ----
    const unsigned mBlocks256 = (unsigned)((NN + 255) / 256);   // 391
    gemm_out_fused<<<dim3(mBlocks256 * 4), dim3(512), 0, stream>>>(
        h, wut, b_upper, hob, wst, b_skip, out, NN);
}

// Round 9
// 866.643 us; speedup vs baseline: 1.1954x; 1.1954x over previous
//
#include <hip/hip_runtime.h>
#include <hip/hip_bf16.h>

#define NN 100000
#define NE 1600000
#define HID 512
#define LOW 128
#define NR  6
#define NBINS (NN * NR)

typedef short  bf16x8 __attribute__((ext_vector_type(8)));
typedef float  f32x4  __attribute__((ext_vector_type(4)));
typedef float  f32x8  __attribute__((ext_vector_type(8)));
typedef unsigned short u16x8 __attribute__((ext_vector_type(8)));

__device__ __forceinline__ unsigned short f2bf(float x) {
    __hip_bfloat16 h = __float2bfloat16(x);
    return __builtin_bit_cast(unsigned short, h);
}
__device__ __forceinline__ float bf2f(unsigned short u) {
    return __builtin_bit_cast(float, (unsigned int)u << 16);
}
__device__ __forceinline__ f32x8 cvt8(u16x8 u) {
    f32x8 r;
    #pragma unroll
    for (int i = 0; i < 8; ++i) r[i] = bf2f(u[i]);
    return r;
}

// ---------------------------------------------------------------------------
// Stage ITERS*32 rows of 128B (64 bf16 cols) into LDS, XOR-swizzled source.
// 256 threads; each iter stages 4 KB (32 rows).
// ---------------------------------------------------------------------------
template<int ITERS>
__device__ __forceinline__ void stage_rows(const unsigned short* __restrict__ G,
                                           int r0, int k0, int Kstride, int Rmax,
                                           char* lds_base, int tid)
{
    #pragma unroll
    for (int is = 0; is < ITERS; ++is) {
        int L   = is * 4096 + tid * 16;
        int row = L >> 7;
        int c   = ((L >> 4) & 7) ^ (row & 7);
        int gr  = r0 + row;
        gr = (gr < Rmax) ? gr : (Rmax - 1);
        const char* src = (const char*)G + ((size_t)gr * Kstride + k0) * 2 + c * 16;
        __builtin_amdgcn_global_load_lds(
            (const __attribute__((address_space(1))) void*)src,
            (__attribute__((address_space(3))) void*)(lds_base + is * 4096 + (tid & 192) * 16),
            16, 0, 0);
    }
}

__device__ __forceinline__ bf16x8 lds_frag(const char* lds_base, int row, int clog)
{
    return *(const bf16x8*)(lds_base + row * 128 + ((clog ^ (row & 7)) << 4));
}

// Bijective XCD-chunked remap (m204 form).
__device__ __forceinline__ int xcd_swizzle(int bid, int nwg)
{
    int q = nwg >> 3, r = nwg & 7;
    int x = bid & 7;
    int base = (x < r) ? x * (q + 1) : r * (q + 1) + (x - r) * q;
    return base + (bid >> 3);
}

// ---------------------------------------------------------------------------
// bf16 MFMA GEMM, BM=128 BN=64 BK=64, 4 waves (2m x 2n), wave tile 64x32.
// C(bf16) = relu(A @ Bt^T + bias) or raw. 1-D grid, XCD swizzle, n-fastest.
// ---------------------------------------------------------------------------
template<bool RELU>
__global__ __launch_bounds__(256, 4)
void gemm_bf16_64(const unsigned short* __restrict__ A,
                  const unsigned short* __restrict__ Bt,
                  const float* __restrict__ bias,
                  unsigned short* __restrict__ C,
                  int M, int N, int K, int nTiles)
{
    __shared__ __align__(16) char lA[16384];
    __shared__ __align__(16) char lB[8192];

    const int tid  = threadIdx.x;
    const int lane = tid & 63;
    const int wid  = tid >> 6;
    const int wm   = wid >> 1;     // 0..1
    const int wn   = wid & 1;      // 0..1

    const int idx = xcd_swizzle(blockIdx.x, gridDim.x);
    const int m0  = (idx / nTiles) * 128;
    const int n0  = (idx % nTiles) * 64;

    f32x4 acc[4][2] = {};

    for (int k0 = 0; k0 < K; k0 += 64) {
        stage_rows<4>(A,  m0, k0, K, M, lA, tid);
        stage_rows<2>(Bt, n0, k0, K, N, lB, tid);
        __syncthreads();
        #pragma unroll
        for (int kk = 0; kk < 2; ++kk) {
            const int clog = kk * 4 + (lane >> 4);
            bf16x8 af[4], bfr[2];
            #pragma unroll
            for (int i = 0; i < 4; ++i)
                af[i] = lds_frag(lA, wm * 64 + i * 16 + (lane & 15), clog);
            #pragma unroll
            for (int j = 0; j < 2; ++j)
                bfr[j] = lds_frag(lB, wn * 32 + j * 16 + (lane & 15), clog);
            #pragma unroll
            for (int i = 0; i < 4; ++i)
                #pragma unroll
                for (int j = 0; j < 2; ++j)
                    acc[i][j] = __builtin_amdgcn_mfma_f32_16x16x32_bf16(
                        af[i], bfr[j], acc[i][j], 0, 0, 0);
        }
        __syncthreads();
    }

    const int col_l = lane & 15;
    const int rgrp  = lane >> 4;
    #pragma unroll
    for (int i = 0; i < 4; ++i) {
        #pragma unroll
        for (int j = 0; j < 2; ++j) {
            int col  = n0 + wn * 32 + j * 16 + col_l;
            float bv = RELU ? bias[col] : 0.f;
            #pragma unroll
            for (int r = 0; r < 4; ++r) {
                int row = m0 + wm * 64 + i * 16 + rgrp * 4 + r;
                if (row < M) {
                    float v = acc[i][j][r];
                    if constexpr (RELU) v = fmaxf(v + bv, 0.f);
                    C[(size_t)row * N + col] = f2bf(v);
                }
            }
        }
    }
}

// ---------------------------------------------------------------------------
// Fused output, BM=128 BN=64: out(f32) = relu(h@Wut^T+bu) + relu(hob@Wst^T+bs)
// launch_bounds(256,3): reg cap ~170 -> no spill with 2 acc sets (~113 regs).
// ---------------------------------------------------------------------------
__global__ __launch_bounds__(256, 3)
void gemm_out_fused(const unsigned short* __restrict__ h,
                    const unsigned short* __restrict__ Wut,
                    const float* __restrict__ bu,
                    const unsigned short* __restrict__ hob,
                    const unsigned short* __restrict__ Wst,
                    const float* __restrict__ bs,
                    float* __restrict__ out, int M)
{
    __shared__ __align__(16) char lA[16384];
    __shared__ __align__(16) char lB[8192];

    const int tid  = threadIdx.x;
    const int lane = tid & 63;
    const int wid  = tid >> 6;
    const int wm   = wid >> 1;
    const int wn   = wid & 1;

    const int idx = xcd_swizzle(blockIdx.x, gridDim.x);
    const int m0  = (idx >> 3) * 128;
    const int n0  = (idx & 7) * 64;

    f32x4 acc1[4][2] = {};
    f32x4 acc2[4][2] = {};

    for (int k0 = 0; k0 < LOW; k0 += 64) {
        stage_rows<4>(h,   m0, k0, LOW, M,   lA, tid);
        stage_rows<2>(Wut, n0, k0, LOW, HID, lB, tid);
        __syncthreads();
        #pragma unroll
        for (int kk = 0; kk < 2; ++kk) {
            const int clog = kk * 4 + (lane >> 4);
            bf16x8 af[4], bfr[2];
            #pragma unroll
            for (int i = 0; i < 4; ++i)
                af[i] = lds_frag(lA, wm * 64 + i * 16 + (lane & 15), clog);
            #pragma unroll
            for (int j = 0; j < 2; ++j)
                bfr[j] = lds_frag(lB, wn * 32 + j * 16 + (lane & 15), clog);
            #pragma unroll
            for (int i = 0; i < 4; ++i)
                #pragma unroll
                for (int j = 0; j < 2; ++j)
                    acc1[i][j] = __builtin_amdgcn_mfma_f32_16x16x32_bf16(
                        af[i], bfr[j], acc1[i][j], 0, 0, 0);
        }
        __syncthreads();
    }
    for (int k0 = 0; k0 < HID; k0 += 64) {
        stage_rows<4>(hob, m0, k0, HID, M,   lA, tid);
        stage_rows<2>(Wst, n0, k0, HID, HID, lB, tid);
        __syncthreads();
        #pragma unroll
        for (int kk = 0; kk < 2; ++kk) {
            const int clog = kk * 4 + (lane >> 4);
            bf16x8 af[4], bfr[2];
            #pragma unroll
            for (int i = 0; i < 4; ++i)
                af[i] = lds_frag(lA, wm * 64 + i * 16 + (lane & 15), clog);
            #pragma unroll
            for (int j = 0; j < 2; ++j)
                bfr[j] = lds_frag(lB, wn * 32 + j * 16 + (lane & 15), clog);
            #pragma unroll
            for (int i = 0; i < 4; ++i)
                #pragma unroll
                for (int j = 0; j < 2; ++j)
                    acc2[i][j] = __builtin_amdgcn_mfma_f32_16x16x32_bf16(
                        af[i], bfr[j], acc2[i][j], 0, 0, 0);
        }
        __syncthreads();
    }

    const int col_l = lane & 15;
    const int rgrp  = lane >> 4;
    #pragma unroll
    for (int i = 0; i < 4; ++i) {
        #pragma unroll
        for (int j = 0; j < 2; ++j) {
            int col   = n0 + wn * 32 + j * 16 + col_l;
            float bv1 = bu[col], bv2 = bs[col];
            #pragma unroll
            for (int r = 0; r < 4; ++r) {
                int row = m0 + wm * 64 + i * 16 + rgrp * 4 + r;
                if (row < M)
                    out[(size_t)row * HID + col] =
                        fmaxf(acc1[i][j][r] + bv1, 0.f) + fmaxf(acc2[i][j][r] + bv2, 0.f);
            }
        }
    }
}

// ---------------------------------------------------------------------------
// Conversions
// ---------------------------------------------------------------------------
__global__ __launch_bounds__(256)
void conv_f32_bf16(const float4* __restrict__ in, ushort4* __restrict__ out, int n4)
{
    for (int i = blockIdx.x * 256 + threadIdx.x; i < n4; i += gridDim.x * 256) {
        float4 v = in[i];
        ushort4 o;
        o.x = f2bf(v.x); o.y = f2bf(v.y); o.z = f2bf(v.z); o.w = f2bf(v.w);
        out[i] = o;
    }
}

__global__ __launch_bounds__(256)
void transpose_bf16(const float* __restrict__ W, unsigned short* __restrict__ Wt,
                    int R, int C)
{
    int idx = blockIdx.x * 256 + threadIdx.x;
    if (idx < R * C) {
        int r = idx / C, c = idx - r * C;
        Wt[(size_t)c * R + r] = f2bf(W[idx]);
    }
}

// ---------------------------------------------------------------------------
// CSR build keyed by bin = dst*NR + rel. Parallel 3-kernel exclusive scan.
// ---------------------------------------------------------------------------
#define SCAN_VT 8
#define SCAN_BS 256
#define SCAN_CHUNK (SCAN_VT * SCAN_BS)
#define SCAN_NB ((NBINS + SCAN_CHUNK - 1) / SCAN_CHUNK)

__global__ __launch_bounds__(256)
void k_hist(const int* __restrict__ dst, const int* __restrict__ typ,
            int* __restrict__ deg, int E)
{
    int e = blockIdx.x * 256 + threadIdx.x;
    if (e < E) atomicAdd(&deg[dst[e] * NR + typ[e]], 1);
}

__global__ __launch_bounds__(SCAN_BS)
void k_scan_part(const int* __restrict__ deg, int* __restrict__ blocksum, int n)
{
    __shared__ int ps[SCAN_BS];
    const int t = threadIdx.x;
    const int lo = blockIdx.x * SCAN_CHUNK + t * SCAN_VT;
    int s = 0;
    #pragma unroll
    for (int k = 0; k < SCAN_VT; ++k) {
        int i = lo + k;
        if (i < n) s += deg[i];
    }
    ps[t] = s;
    __syncthreads();
    for (int off = SCAN_BS / 2; off > 0; off >>= 1) {
        if (t < off) ps[t] += ps[t + off];
        __syncthreads();
    }
    if (t == 0) blocksum[blockIdx.x] = ps[0];
}

__global__ __launch_bounds__(64)
void k_scan_mid(const int* __restrict__ blocksum, int* __restrict__ blockoff,
                int* __restrict__ rowstart, int nb, int n)
{
    if (threadIdx.x == 0) {
        int run = 0;
        for (int i = 0; i < nb; ++i) { blockoff[i] = run; run += blocksum[i]; }
        rowstart[n] = run;
    }
}

__global__ __launch_bounds__(SCAN_BS)
void k_scan_final(const int* __restrict__ deg, const int* __restrict__ blockoff,
                  int* __restrict__ rowstart, int* __restrict__ cursor, int n)
{
    __shared__ int ps[SCAN_BS];
    const int t = threadIdx.x;
    const int lo = blockIdx.x * SCAN_CHUNK + t * SCAN_VT;
    int local[SCAN_VT];
    int s = 0;
    #pragma unroll
    for (int k = 0; k < SCAN_VT; ++k) {
        int i = lo + k;
        int v = (i < n) ? deg[i] : 0;
        local[k] = v;
        s += v;
    }
    ps[t] = s;
    __syncthreads();
    for (int off = 1; off < SCAN_BS; off <<= 1) {
        int v = (t >= off) ? ps[t - off] : 0;
        __syncthreads();
        ps[t] += v;
        __syncthreads();
    }
    int run = blockoff[blockIdx.x] + ((t > 0) ? ps[t - 1] : 0);
    #pragma unroll
    for (int k = 0; k < SCAN_VT; ++k) {
        int i = lo + k;
        if (i < n) {
            rowstart[i] = run;
            cursor[i]   = run;
            run += local[k];
        }
    }
}

__global__ __launch_bounds__(256)
void k_fill(const int* __restrict__ src, const int* __restrict__ dst,
            const int* __restrict__ typ, int* __restrict__ cursor,
            int* __restrict__ list, int E)
{
    int e = blockIdx.x * 256 + threadIdx.x;
    if (e < E) {
        int pos = atomicAdd(&cursor[dst[e] * NR + typ[e]], 1);
        list[pos] = src[e];
    }
}

// ---------------------------------------------------------------------------
// Gather-aggregate: QUARTER-WAVE (16 lanes) per dst node; lane owns channels
// 8c..8c+7 (ushort8, 16 lanes x 16B = one 256B row). 6 relation chains
// concurrent -> each load instruction touches FOUR rows (4 nodes per wave).
// ---------------------------------------------------------------------------
__global__ __launch_bounds__(256)
void gather_agg(const unsigned short* __restrict__ h,
                const int* __restrict__ rowstart,
                const int* __restrict__ list,
                unsigned short* __restrict__ S)
{
    const int v = (blockIdx.x * 256 + threadIdx.x) >> 4;   // quarter-wave/node
    const int lane = threadIdx.x & 15;
    const u16x8* hp = (const u16x8*)h;                     // 16 u16x8 per row

    const int b0 = rowstart[v * NR + 0];
    const int b1 = rowstart[v * NR + 1];
    const int b2 = rowstart[v * NR + 2];
    const int b3 = rowstart[v * NR + 3];
    const int b4 = rowstart[v * NR + 4];
    const int b5 = rowstart[v * NR + 5];
    const int b6 = rowstart[v * NR + 6];
    const int n0 = b1 - b0, n1 = b2 - b1, n2 = b3 - b2;
    const int n3 = b4 - b3, n4 = b5 - b4, n5 = b6 - b5;
    const int kmax = max(max(max(n0, n1), max(n2, n3)), max(n4, n5));

    f32x8 a0 = {}, a1 = {}, a2 = {}, a3 = {}, a4 = {}, a5 = {};

    for (int k = 0; k < kmax; ++k) {
        int i0 = (k < n0) ? (b0 + k) : 0;
        int i1 = (k < n1) ? (b1 + k) : 0;
        int i2 = (k < n2) ? (b2 + k) : 0;
        int i3 = (k < n3) ? (b3 + k) : 0;
        int i4 = (k < n4) ? (b4 + k) : 0;
        int i5 = (k < n5) ? (b5 + k) : 0;
        int s0 = list[i0], s1 = list[i1], s2 = list[i2];
        int s3 = list[i3], s4 = list[i4], s5 = list[i5];
        u16x8 u0 = hp[(size_t)s0 * 16 + lane];
        u16x8 u1 = hp[(size_t)s1 * 16 + lane];
        u16x8 u2 = hp[(size_t)s2 * 16 + lane];
        u16x8 u3 = hp[(size_t)s3 * 16 + lane];
        u16x8 u4 = hp[(size_t)s4 * 16 + lane];
        u16x8 u5 = hp[(size_t)s5 * 16 + lane];
        if (k < n0) a0 += cvt8(u0);
        if (k < n1) a1 += cvt8(u1);
        if (k < n2) a2 += cvt8(u2);
        if (k < n3) a3 += cvt8(u3);
        if (k < n4) a4 += cvt8(u4);
        if (k < n5) a5 += cvt8(u5);
    }

    u16x8* o = (u16x8*)(S + (size_t)v * (NR * LOW));
    u16x8 w;
    #pragma unroll
    for (int i = 0; i < 8; ++i) w[i] = f2bf(a0[i]);
    o[0 * 16 + lane] = w;
    #pragma unroll
    for (int i = 0; i < 8; ++i) w[i] = f2bf(a1[i]);
    o[1 * 16 + lane] = w;
    #pragma unroll
    for (int i = 0; i < 8; ++i) w[i] = f2bf(a2[i]);
    o[2 * 16 + lane] = w;
    #pragma unroll
    for (int i = 0; i < 8; ++i) w[i] = f2bf(a3[i]);
    o[3 * 16 + lane] = w;
    #pragma unroll
    for (int i = 0; i < 8; ++i) w[i] = f2bf(a4[i]);
    o[4 * 16 + lane] = w;
    #pragma unroll
    for (int i = 0; i < 8; ++i) w[i] = f2bf(a5[i]);
    o[5 * 16 + lane] = w;
}

extern "C" void kernel_launch(void* const* d_in, const int* in_sizes, int n_in,
                              void* d_out, int out_size, void* d_ws, size_t ws_size,
                              hipStream_t stream)
{
    (void)in_sizes; (void)n_in; (void)out_size; (void)ws_size;

    const float* h_origin = (const float*)d_in[0];
    const int*   esrc     = (const int*)d_in[1];
    const int*   edst     = (const int*)d_in[2];
    const int*   etyp     = (const int*)d_in[3];
    const float* W_lower  = (const float*)d_in[4];
    const float* b_lower  = (const float*)d_in[5];
    const float* Wl[3]    = {(const float*)d_in[6], (const float*)d_in[8], (const float*)d_in[10]};
    const float* bl[3]    = {(const float*)d_in[7], (const float*)d_in[9], (const float*)d_in[11]};
    const float* W_upper  = (const float*)d_in[12];
    const float* b_upper  = (const float*)d_in[13];
    const float* W_skip   = (const float*)d_in[14];
    const float* b_skip   = (const float*)d_in[15];
    float*       out      = (float*)d_out;

    // Workspace layout
    unsigned short* hob = (unsigned short*)d_ws;          // [NN,512] bf16
    unsigned short* h   = hob + (size_t)NN * HID;         // [NN,128]
    unsigned short* S   = h + (size_t)NN * LOW;           // [NN,768]
    unsigned short* wlt = S + (size_t)NN * NR * LOW;      // [128,512]
    unsigned short* w1t = wlt + (size_t)LOW * HID;        // [128,768]^T x3
    unsigned short* w2t = w1t + (size_t)LOW * NR * LOW;
    unsigned short* w3t = w2t + (size_t)LOW * NR * LOW;
    unsigned short* wut = w3t + (size_t)LOW * NR * LOW;   // [512,128]
    unsigned short* wst = wut + (size_t)HID * LOW;        // [512,512]
    int* deg      = (int*)(wst + (size_t)HID * HID);      // [NBINS]
    int* rowstart = deg + NBINS;                          // [NBINS+1]
    int* cursor   = rowstart + NBINS + 1;                 // [NBINS]
    int* list     = cursor + NBINS;                       // [NE]
    int* blocksum = list + NE;                            // [SCAN_NB]
    int* blockoff = blocksum + SCAN_NB;                   // [SCAN_NB]
    unsigned short* wtL[3] = {w1t, w2t, w3t};

    const unsigned eBlocks = (unsigned)((NE + 255) / 256);
    const unsigned mBlocks = (unsigned)((NN + 127) / 128);   // 782

    // ---- conversions ----
    conv_f32_bf16<<<dim3(2048), dim3(256), 0, stream>>>(
        (const float4*)h_origin, (ushort4*)hob, NN * HID / 4);
    transpose_bf16<<<dim3((HID * LOW + 255) / 256), dim3(256), 0, stream>>>(
        W_lower, wlt, HID, LOW);
    for (int L = 0; L < 3; ++L)
        transpose_bf16<<<dim3((NR * LOW * LOW + 255) / 256), dim3(256), 0, stream>>>(
            Wl[L], wtL[L], NR * LOW, LOW);
    transpose_bf16<<<dim3((LOW * HID + 255) / 256), dim3(256), 0, stream>>>(
        W_upper, wut, LOW, HID);
    transpose_bf16<<<dim3((HID * HID + 255) / 256), dim3(256), 0, stream>>>(
        W_skip, wst, HID, HID);

    // ---- CSR build over (dst, rel) bins ----
    hipMemsetAsync(deg, 0, NBINS * sizeof(int), stream);
    k_hist<<<dim3(eBlocks), dim3(256), 0, stream>>>(edst, etyp, deg, NE);
    k_scan_part<<<dim3(SCAN_NB), dim3(SCAN_BS), 0, stream>>>(deg, blocksum, NBINS);
    k_scan_mid<<<dim3(1), dim3(64), 0, stream>>>(blocksum, blockoff, rowstart, SCAN_NB, NBINS);
    k_scan_final<<<dim3(SCAN_NB), dim3(SCAN_BS), 0, stream>>>(deg, blockoff, rowstart, cursor, NBINS);
    k_fill<<<dim3(eBlocks), dim3(256), 0, stream>>>(esrc, edst, etyp, cursor, list, NE);

    // ---- lower: h = relu(hob @ wlt^T + b_lower), N=128 -> 2 n-tiles ----
    gemm_bf16_64<true><<<dim3(mBlocks * 2), dim3(256), 0, stream>>>(
        hob, wlt, b_lower, h, NN, LOW, HID, 2);

    // ---- 3 R-GCN layers ----
    const unsigned gBlocks = (unsigned)(((size_t)NN * 16 + 255) / 256);  // 6250
    for (int L = 0; L < 3; ++L) {
        gather_agg<<<dim3(gBlocks), dim3(256), 0, stream>>>(h, rowstart, list, S);
        gemm_bf16_64<true><<<dim3(mBlocks * 2), dim3(256), 0, stream>>>(
            S, wtL[L], bl[L], h, NN, LOW, NR * LOW, 2);
    }

    // ---- fused output: N=512 -> 8 n-tiles ----
    gemm_out_fused<<<dim3(mBlocks * 8), dim3(256), 0, stream>>>(
        h, wut, b_upper, hob, wst, b_skip, out, NN);
}

// Round 10
// 834.662 us; speedup vs baseline: 1.2412x; 1.0383x over previous
//
#include <hip/hip_runtime.h>
#include <hip/hip_bf16.h>

#define NN 100000
#define NE 1600000
#define HID 512
#define LOW 128
#define NR  6
#define NBINS (NN * NR)

typedef short  bf16x8 __attribute__((ext_vector_type(8)));
typedef float  f32x4  __attribute__((ext_vector_type(4)));
typedef float  f32x8  __attribute__((ext_vector_type(8)));
typedef unsigned short u16x8 __attribute__((ext_vector_type(8)));

__device__ __forceinline__ unsigned short f2bf(float x) {
    __hip_bfloat16 h = __float2bfloat16(x);
    return __builtin_bit_cast(unsigned short, h);
}
__device__ __forceinline__ float bf2f(unsigned short u) {
    return __builtin_bit_cast(float, (unsigned int)u << 16);
}
__device__ __forceinline__ f32x8 cvt8(u16x8 u) {
    f32x8 r;
    #pragma unroll
    for (int i = 0; i < 8; ++i) r[i] = bf2f(u[i]);
    return r;
}

// ---------------------------------------------------------------------------
// Stage ITERS*32 rows of 128B (64 bf16 cols) into LDS, XOR-swizzled source
// (global_load_lds writes linearly: wave-uniform base + lane*16).
// ---------------------------------------------------------------------------
template<int ITERS>
__device__ __forceinline__ void stage_rows(const unsigned short* __restrict__ G,
                                           int r0, int k0, int Kstride, int Rmax,
                                           char* lds_base, int tid)
{
    #pragma unroll
    for (int is = 0; is < ITERS; ++is) {
        int L   = is * 4096 + tid * 16;
        int row = L >> 7;
        int c   = ((L >> 4) & 7) ^ (row & 7);
        int gr  = r0 + row;
        gr = (gr < Rmax) ? gr : (Rmax - 1);
        const char* src = (const char*)G + ((size_t)gr * Kstride + k0) * 2 + c * 16;
        __builtin_amdgcn_global_load_lds(
            (const __attribute__((address_space(1))) void*)src,
            (__attribute__((address_space(3))) void*)(lds_base + is * 4096 + (tid & 192) * 16),
            16, 0, 0);
    }
}

__device__ __forceinline__ bf16x8 lds_frag(const char* lds_base, int row, int clog)
{
    return *(const bf16x8*)(lds_base + row * 128 + ((clog ^ (row & 7)) << 4));
}

// ---------------------------------------------------------------------------
// bf16 MFMA GEMM: C(bf16) = relu(A @ Bt^T + bias). 128x128 tile, 4 waves.
// (round-7 geometry: proven fastest of BM/BN variants tried)
// ---------------------------------------------------------------------------
__global__ __launch_bounds__(256, 2)
void gemm_bf16(const unsigned short* __restrict__ A,
               const unsigned short* __restrict__ Bt,
               const float* __restrict__ bias,
               unsigned short* __restrict__ C,
               int M, int N, int K)
{
    __shared__ __align__(16) char lA[16384];
    __shared__ __align__(16) char lB[16384];

    const int tid  = threadIdx.x;
    const int lane = tid & 63;
    const int wid  = tid >> 6;
    const int wm   = wid >> 1;
    const int wn   = wid & 1;
    const int m0   = blockIdx.y * 128;
    const int n0   = blockIdx.x * 128;

    f32x4 acc[4][4] = {};

    for (int k0 = 0; k0 < K; k0 += 64) {
        stage_rows<4>(A,  m0, k0, K, M, lA, tid);
        stage_rows<4>(Bt, n0, k0, K, N, lB, tid);
        __syncthreads();
        #pragma unroll
        for (int kk = 0; kk < 2; ++kk) {
            const int clog = kk * 4 + (lane >> 4);
            bf16x8 af[4], bfr[4];
            #pragma unroll
            for (int i = 0; i < 4; ++i)
                af[i] = lds_frag(lA, wm * 64 + i * 16 + (lane & 15), clog);
            #pragma unroll
            for (int j = 0; j < 4; ++j)
                bfr[j] = lds_frag(lB, wn * 64 + j * 16 + (lane & 15), clog);
            #pragma unroll
            for (int i = 0; i < 4; ++i)
                #pragma unroll
                for (int j = 0; j < 4; ++j)
                    acc[i][j] = __builtin_amdgcn_mfma_f32_16x16x32_bf16(
                        af[i], bfr[j], acc[i][j], 0, 0, 0);
        }
        __syncthreads();
    }

    const int col_l = lane & 15;
    const int rgrp  = lane >> 4;
    #pragma unroll
    for (int i = 0; i < 4; ++i) {
        #pragma unroll
        for (int j = 0; j < 4; ++j) {
            int col  = n0 + wn * 64 + j * 16 + col_l;
            float bv = bias[col];
            #pragma unroll
            for (int r = 0; r < 4; ++r) {
                int row = m0 + wm * 64 + i * 16 + rgrp * 4 + r;
                if (row < M)
                    C[(size_t)row * N + col] = f2bf(fmaxf(acc[i][j][r] + bv, 0.f));
            }
        }
    }
}

// ---------------------------------------------------------------------------
// Fused output (round-7 geometry + NT out stores):
// out(f32) = relu(h @ Wut^T + bu) + relu(hob @ Wst^T + bs)
// 1-D grid, XCD swizzle (nwg=3128, %8==0): 4 n-tiles of each hob slab share XCD.
// ---------------------------------------------------------------------------
__global__ __launch_bounds__(256, 2)
void gemm_out_fused(const unsigned short* __restrict__ h,
                    const unsigned short* __restrict__ Wut,
                    const float* __restrict__ bu,
                    const unsigned short* __restrict__ hob,
                    const unsigned short* __restrict__ Wst,
                    const float* __restrict__ bs,
                    float* __restrict__ out, int M)
{
    __shared__ __align__(16) char lA[16384];
    __shared__ __align__(16) char lB[16384];

    const int tid  = threadIdx.x;
    const int lane = tid & 63;
    const int wid  = tid >> 6;
    const int wm   = wid >> 1;
    const int wn   = wid & 1;

    const int nwg  = gridDim.x;            // 3128 = 8 * 391
    const int cpx  = nwg >> 3;
    const int idx  = (blockIdx.x & 7) * cpx + (blockIdx.x >> 3);
    const int m0   = (idx >> 2) * 128;
    const int n0   = (idx & 3) * 128;

    f32x4 acc1[4][4] = {};
    f32x4 acc2[4][4] = {};

    for (int k0 = 0; k0 < LOW; k0 += 64) {
        stage_rows<4>(h,   m0, k0, LOW, M,   lA, tid);
        stage_rows<4>(Wut, n0, k0, LOW, HID, lB, tid);
        __syncthreads();
        #pragma unroll
        for (int kk = 0; kk < 2; ++kk) {
            const int clog = kk * 4 + (lane >> 4);
            bf16x8 af[4], bfr[4];
            #pragma unroll
            for (int i = 0; i < 4; ++i)
                af[i] = lds_frag(lA, wm * 64 + i * 16 + (lane & 15), clog);
            #pragma unroll
            for (int j = 0; j < 4; ++j)
                bfr[j] = lds_frag(lB, wn * 64 + j * 16 + (lane & 15), clog);
            #pragma unroll
            for (int i = 0; i < 4; ++i)
                #pragma unroll
                for (int j = 0; j < 4; ++j)
                    acc1[i][j] = __builtin_amdgcn_mfma_f32_16x16x32_bf16(
                        af[i], bfr[j], acc1[i][j], 0, 0, 0);
        }
        __syncthreads();
    }
    for (int k0 = 0; k0 < HID; k0 += 64) {
        stage_rows<4>(hob, m0, k0, HID, M,   lA, tid);
        stage_rows<4>(Wst, n0, k0, HID, HID, lB, tid);
        __syncthreads();
        #pragma unroll
        for (int kk = 0; kk < 2; ++kk) {
            const int clog = kk * 4 + (lane >> 4);
            bf16x8 af[4], bfr[4];
            #pragma unroll
            for (int i = 0; i < 4; ++i)
                af[i] = lds_frag(lA, wm * 64 + i * 16 + (lane & 15), clog);
            #pragma unroll
            for (int j = 0; j < 4; ++j)
                bfr[j] = lds_frag(lB, wn * 64 + j * 16 + (lane & 15), clog);
            #pragma unroll
            for (int i = 0; i < 4; ++i)
                #pragma unroll
                for (int j = 0; j < 4; ++j)
                    acc2[i][j] = __builtin_amdgcn_mfma_f32_16x16x32_bf16(
                        af[i], bfr[j], acc2[i][j], 0, 0, 0);
        }
        __syncthreads();
    }

    const int col_l = lane & 15;
    const int rgrp  = lane >> 4;
    #pragma unroll
    for (int i = 0; i < 4; ++i) {
        #pragma unroll
        for (int j = 0; j < 4; ++j) {
            int col   = n0 + wn * 64 + j * 16 + col_l;
            float bv1 = bu[col], bv2 = bs[col];
            #pragma unroll
            for (int r = 0; r < 4; ++r) {
                int row = m0 + wm * 64 + i * 16 + rgrp * 4 + r;
                if (row < M) {
                    float v = fmaxf(acc1[i][j][r] + bv1, 0.f) +
                              fmaxf(acc2[i][j][r] + bv2, 0.f);
                    __builtin_nontemporal_store(v, &out[(size_t)row * HID + col]);
                }
            }
        }
    }
}

// ---------------------------------------------------------------------------
// Conversions
// ---------------------------------------------------------------------------
__global__ __launch_bounds__(256)
void conv_f32_bf16(const float4* __restrict__ in, ushort4* __restrict__ out, int n4)
{
    for (int i = blockIdx.x * 256 + threadIdx.x; i < n4; i += gridDim.x * 256) {
        float4 v = in[i];
        ushort4 o;
        o.x = f2bf(v.x); o.y = f2bf(v.y); o.z = f2bf(v.z); o.w = f2bf(v.w);
        out[i] = o;
    }
}

__global__ __launch_bounds__(256)
void transpose_bf16(const float* __restrict__ W, unsigned short* __restrict__ Wt,
                    int R, int C)
{
    int idx = blockIdx.x * 256 + threadIdx.x;
    if (idx < R * C) {
        int r = idx / C, c = idx - r * C;
        Wt[(size_t)c * R + r] = f2bf(W[idx]);
    }
}

// ---------------------------------------------------------------------------
// CSR build keyed by bin = dst*NR + rel. Parallel 3-kernel exclusive scan.
// ---------------------------------------------------------------------------
#define SCAN_VT 8
#define SCAN_BS 256
#define SCAN_CHUNK (SCAN_VT * SCAN_BS)
#define SCAN_NB ((NBINS + SCAN_CHUNK - 1) / SCAN_CHUNK)

__global__ __launch_bounds__(256)
void k_hist(const int* __restrict__ dst, const int* __restrict__ typ,
            int* __restrict__ deg, int E)
{
    int e = blockIdx.x * 256 + threadIdx.x;
    if (e < E) atomicAdd(&deg[dst[e] * NR + typ[e]], 1);
}

__global__ __launch_bounds__(SCAN_BS)
void k_scan_part(const int* __restrict__ deg, int* __restrict__ blocksum, int n)
{
    __shared__ int ps[SCAN_BS];
    const int t = threadIdx.x;
    const int lo = blockIdx.x * SCAN_CHUNK + t * SCAN_VT;
    int s = 0;
    #pragma unroll
    for (int k = 0; k < SCAN_VT; ++k) {
        int i = lo + k;
        if (i < n) s += deg[i];
    }
    ps[t] = s;
    __syncthreads();
    for (int off = SCAN_BS / 2; off > 0; off >>= 1) {
        if (t < off) ps[t] += ps[t + off];
        __syncthreads();
    }
    if (t == 0) blocksum[blockIdx.x] = ps[0];
}

__global__ __launch_bounds__(64)
void k_scan_mid(const int* __restrict__ blocksum, int* __restrict__ blockoff,
                int* __restrict__ rowstart, int nb, int n)
{
    if (threadIdx.x == 0) {
        int run = 0;
        for (int i = 0; i < nb; ++i) { blockoff[i] = run; run += blocksum[i]; }
        rowstart[n] = run;
    }
}

__global__ __launch_bounds__(SCAN_BS)
void k_scan_final(const int* __restrict__ deg, const int* __restrict__ blockoff,
                  int* __restrict__ rowstart, int* __restrict__ cursor, int n)
{
    __shared__ int ps[SCAN_BS];
    const int t = threadIdx.x;
    const int lo = blockIdx.x * SCAN_CHUNK + t * SCAN_VT;
    int local[SCAN_VT];
    int s = 0;
    #pragma unroll
    for (int k = 0; k < SCAN_VT; ++k) {
        int i = lo + k;
        int v = (i < n) ? deg[i] : 0;
        local[k] = v;
        s += v;
    }
    ps[t] = s;
    __syncthreads();
    for (int off = 1; off < SCAN_BS; off <<= 1) {
        int v = (t >= off) ? ps[t - off] : 0;
        __syncthreads();
        ps[t] += v;
        __syncthreads();
    }
    int run = blockoff[blockIdx.x] + ((t > 0) ? ps[t - 1] : 0);
    #pragma unroll
    for (int k = 0; k < SCAN_VT; ++k) {
        int i = lo + k;
        if (i < n) {
            rowstart[i] = run;
            cursor[i]   = run;
            run += local[k];
        }
    }
}

__global__ __launch_bounds__(256)
void k_fill(const int* __restrict__ src, const int* __restrict__ dst,
            const int* __restrict__ typ, int* __restrict__ cursor,
            int* __restrict__ list, int E)
{
    int e = blockIdx.x * 256 + threadIdx.x;
    if (e < E) {
        int pos = atomicAdd(&cursor[dst[e] * NR + typ[e]], 1);
        list[pos] = src[e];
    }
}

// ---------------------------------------------------------------------------
// Gather-aggregate: QUARTER-WAVE (16 lanes) per dst node; lane owns channels
// 8c..8c+7 (ushort8). 6 relation chains concurrent -> each load touches FOUR
// rows. S written with NON-TEMPORAL stores so the 150 MB stream doesn't evict
// the L3-resident h (the random-read working set).
// ---------------------------------------------------------------------------
__global__ __launch_bounds__(256)
void gather_agg(const unsigned short* __restrict__ h,
                const int* __restrict__ rowstart,
                const int* __restrict__ list,
                unsigned short* __restrict__ S)
{
    const int v = (blockIdx.x * 256 + threadIdx.x) >> 4;   // NN*16 == grid*256
    const int lane = threadIdx.x & 15;
    const u16x8* hp = (const u16x8*)h;

    const int b0 = rowstart[v * NR + 0];
    const int b1 = rowstart[v * NR + 1];
    const int b2 = rowstart[v * NR + 2];
    const int b3 = rowstart[v * NR + 3];
    const int b4 = rowstart[v * NR + 4];
    const int b5 = rowstart[v * NR + 5];
    const int b6 = rowstart[v * NR + 6];
    const int n0 = b1 - b0, n1 = b2 - b1, n2 = b3 - b2;
    const int n3 = b4 - b3, n4 = b5 - b4, n5 = b6 - b5;
    const int kmax = max(max(max(n0, n1), max(n2, n3)), max(n4, n5));

    f32x8 a0 = {}, a1 = {}, a2 = {}, a3 = {}, a4 = {}, a5 = {};

    for (int k = 0; k < kmax; ++k) {
        int i0 = (k < n0) ? (b0 + k) : 0;
        int i1 = (k < n1) ? (b1 + k) : 0;
        int i2 = (k < n2) ? (b2 + k) : 0;
        int i3 = (k < n3) ? (b3 + k) : 0;
        int i4 = (k < n4) ? (b4 + k) : 0;
        int i5 = (k < n5) ? (b5 + k) : 0;
        int s0 = list[i0], s1 = list[i1], s2 = list[i2];
        int s3 = list[i3], s4 = list[i4], s5 = list[i5];
        u16x8 u0 = hp[(size_t)s0 * 16 + lane];
        u16x8 u1 = hp[(size_t)s1 * 16 + lane];
        u16x8 u2 = hp[(size_t)s2 * 16 + lane];
        u16x8 u3 = hp[(size_t)s3 * 16 + lane];
        u16x8 u4 = hp[(size_t)s4 * 16 + lane];
        u16x8 u5 = hp[(size_t)s5 * 16 + lane];
        if (k < n0) a0 += cvt8(u0);
        if (k < n1) a1 += cvt8(u1);
        if (k < n2) a2 += cvt8(u2);
        if (k < n3) a3 += cvt8(u3);
        if (k < n4) a4 += cvt8(u4);
        if (k < n5) a5 += cvt8(u5);
    }

    u16x8* o = (u16x8*)(S + (size_t)v * (NR * LOW));
    u16x8 w;
    #pragma unroll
    for (int i = 0; i < 8; ++i) w[i] = f2bf(a0[i]);
    __builtin_nontemporal_store(w, &o[0 * 16 + lane]);
    #pragma unroll
    for (int i = 0; i < 8; ++i) w[i] = f2bf(a1[i]);
    __builtin_nontemporal_store(w, &o[1 * 16 + lane]);
    #pragma unroll
    for (int i = 0; i < 8; ++i) w[i] = f2bf(a2[i]);
    __builtin_nontemporal_store(w, &o[2 * 16 + lane]);
    #pragma unroll
    for (int i = 0; i < 8; ++i) w[i] = f2bf(a3[i]);
    __builtin_nontemporal_store(w, &o[3 * 16 + lane]);
    #pragma unroll
    for (int i = 0; i < 8; ++i) w[i] = f2bf(a4[i]);
    __builtin_nontemporal_store(w, &o[4 * 16 + lane]);
    #pragma unroll
    for (int i = 0; i < 8; ++i) w[i] = f2bf(a5[i]);
    __builtin_nontemporal_store(w, &o[5 * 16 + lane]);
}

extern "C" void kernel_launch(void* const* d_in, const int* in_sizes, int n_in,
                              void* d_out, int out_size, void* d_ws, size_t ws_size,
                              hipStream_t stream)
{
    (void)in_sizes; (void)n_in; (void)out_size; (void)ws_size;

    const float* h_origin = (const float*)d_in[0];
    const int*   esrc     = (const int*)d_in[1];
    const int*   edst     = (const int*)d_in[2];
    const int*   etyp     = (const int*)d_in[3];
    const float* W_lower  = (const float*)d_in[4];
    const float* b_lower  = (const float*)d_in[5];
    const float* Wl[3]    = {(const float*)d_in[6], (const float*)d_in[8], (const float*)d_in[10]};
    const float* bl[3]    = {(const float*)d_in[7], (const float*)d_in[9], (const float*)d_in[11]};
    const float* W_upper  = (const float*)d_in[12];
    const float* b_upper  = (const float*)d_in[13];
    const float* W_skip   = (const float*)d_in[14];
    const float* b_skip   = (const float*)d_in[15];
    float*       out      = (float*)d_out;

    // Workspace layout
    unsigned short* hob = (unsigned short*)d_ws;          // [NN,512] bf16
    unsigned short* h   = hob + (size_t)NN * HID;         // [NN,128]
    unsigned short* S   = h + (size_t)NN * LOW;           // [NN,768]
    unsigned short* wlt = S + (size_t)NN * NR * LOW;      // [128,512]
    unsigned short* w1t = wlt + (size_t)LOW * HID;        // [128,768]^T x3
    unsigned short* w2t = w1t + (size_t)LOW * NR * LOW;
    unsigned short* w3t = w2t + (size_t)LOW * NR * LOW;
    unsigned short* wut = w3t + (size_t)LOW * NR * LOW;   // [512,128]
    unsigned short* wst = wut + (size_t)HID * LOW;        // [512,512]
    int* deg      = (int*)(wst + (size_t)HID * HID);      // [NBINS]
    int* rowstart = deg + NBINS;                          // [NBINS+1]
    int* cursor   = rowstart + NBINS + 1;                 // [NBINS]
    int* list     = cursor + NBINS;                       // [NE]
    int* blocksum = list + NE;                            // [SCAN_NB]
    int* blockoff = blocksum + SCAN_NB;                   // [SCAN_NB]
    unsigned short* wtL[3] = {w1t, w2t, w3t};

    const unsigned eBlocks = (unsigned)((NE + 255) / 256);
    const unsigned mBlocks = (unsigned)((NN + 127) / 128);   // 782

    // ---- conversions ----
    conv_f32_bf16<<<dim3(2048), dim3(256), 0, stream>>>(
        (const float4*)h_origin, (ushort4*)hob, NN * HID / 4);
    transpose_bf16<<<dim3((HID * LOW + 255) / 256), dim3(256), 0, stream>>>(
        W_lower, wlt, HID, LOW);
    for (int L = 0; L < 3; ++L)
        transpose_bf16<<<dim3((NR * LOW * LOW + 255) / 256), dim3(256), 0, stream>>>(
            Wl[L], wtL[L], NR * LOW, LOW);
    transpose_bf16<<<dim3((LOW * HID + 255) / 256), dim3(256), 0, stream>>>(
        W_upper, wut, LOW, HID);
    transpose_bf16<<<dim3((HID * HID + 255) / 256), dim3(256), 0, stream>>>(
        W_skip, wst, HID, HID);

    // ---- CSR build over (dst, rel) bins ----
    hipMemsetAsync(deg, 0, NBINS * sizeof(int), stream);
    k_hist<<<dim3(eBlocks), dim3(256), 0, stream>>>(edst, etyp, deg, NE);
    k_scan_part<<<dim3(SCAN_NB), dim3(SCAN_BS), 0, stream>>>(deg, blocksum, NBINS);
    k_scan_mid<<<dim3(1), dim3(64), 0, stream>>>(blocksum, blockoff, rowstart, SCAN_NB, NBINS);
    k_scan_final<<<dim3(SCAN_NB), dim3(SCAN_BS), 0, stream>>>(deg, blockoff, rowstart, cursor, NBINS);
    k_fill<<<dim3(eBlocks), dim3(256), 0, stream>>>(esrc, edst, etyp, cursor, list, NE);

    // ---- lower: h = relu(hob @ wlt^T + b_lower) ----
    gemm_bf16<<<dim3(1, mBlocks), dim3(256), 0, stream>>>(
        hob, wlt, b_lower, h, NN, LOW, HID);

    // ---- 3 R-GCN layers ----
    const unsigned gBlocks = (unsigned)(((size_t)NN * 16 + 255) / 256);  // 6250
    for (int L = 0; L < 3; ++L) {
        gather_agg<<<dim3(gBlocks), dim3(256), 0, stream>>>(h, rowstart, list, S);
        gemm_bf16<<<dim3(1, mBlocks), dim3(256), 0, stream>>>(
            S, wtL[L], bl[L], h, NN, LOW, NR * LOW);
    }

    // ---- fused output (1-D grid, XCD swizzle, NT out stores) ----
    gemm_out_fused<<<dim3((HID / 128) * mBlocks), dim3(256), 0, stream>>>(
        h, wut, b_upper, hob, wst, b_skip, out, NN);
}